// Round 1
// baseline (233.263 us; speedup 1.0000x reference)
//
#include <hip/hip_runtime.h>
#include <math.h>

#define SCALE_MIN 0.5f
#define SCALE_MAX 15.0f
#define MULTIPLIER 0.1f
#define EPS 1e-8f

// Output layout (flat concat, f32):
//   means      [BN*3]  @ 0
//   cov        [BN*9]  @ 3*BN
//   harmonics  [BN*12] @ 12*BN
//   opacities  [BN*1]  @ 24*BN
//   scales     [BN*3]  @ 25*BN
//   rotations  [BN*4]  @ 28*BN
__global__ __launch_bounds__(256) void mono_gaussian_adapter_kernel(
    const float* __restrict__ ext,    // B*16 (B,1,4,4)
    const float* __restrict__ intr,   // B*9  (B,1,3,3)
    const float* __restrict__ coord,  // BN*2
    const float* __restrict__ depth,  // BN
    const float* __restrict__ opac,   // BN
    const float* __restrict__ rawg,   // BN*19
    const int* __restrict__ hp,
    const int* __restrict__ wp,
    float* __restrict__ out,
    int bpb,                          // blocks per batch (N/256)
    int BN)
{
    int gid = blockIdx.x * 256 + threadIdx.x;
    if (gid >= BN) return;
    int b = blockIdx.x / bpb;         // block-uniform -> scalar path

    float inv_w = 1.0f / (float)wp[0];
    float inv_h = 1.0f / (float)hp[0];

    // ---- per-batch (block-uniform) constants ----
    const float* E = ext + b * 16;
    float c00=E[0],  c01=E[1],  c02=E[2],  t0=E[3];
    float c10=E[4],  c11=E[5],  c12=E[6],  t1=E[7];
    float c20=E[8],  c21=E[9],  c22=E[10], t2=E[11];

    const float* Kb = intr + b * 9;
    float k00=Kb[0],k01=Kb[1],k02=Kb[2];
    float k10=Kb[3],k11=Kb[4],k12=Kb[5];
    float k20=Kb[6],k21=Kb[7],k22=Kb[8];

    // multiplier = 0.1 * sum(inv(K[:2,:2]) @ [1/w,1/h])
    float det2 = k00*k11 - k01*k10;
    float mult = MULTIPLIER * ((k11*inv_w - k01*inv_h) + (k00*inv_h - k10*inv_w)) / det2;

    // full 3x3 inverse of K
    float det3 = k00*(k11*k22 - k12*k21)
               + k01*(k12*k20 - k10*k22)
               + k02*(k10*k21 - k11*k20);
    float id3 = 1.0f / det3;
    float i00 = (k11*k22 - k12*k21)*id3;
    float i01 = (k02*k21 - k01*k22)*id3;
    float i02 = (k01*k12 - k02*k11)*id3;
    float i10 = (k12*k20 - k10*k22)*id3;
    float i11 = (k00*k22 - k02*k20)*id3;
    float i12 = (k02*k10 - k00*k12)*id3;
    float i20 = (k10*k21 - k11*k20)*id3;
    float i21 = (k01*k20 - k00*k21)*id3;
    float i22 = (k00*k11 - k01*k10)*id3;

    // ---- per-gaussian loads ----
    float2 uv = ((const float2*)coord)[gid];
    float dep = depth[gid];
    float op  = opac[gid];
    const float* g = rawg + (long long)gid * 19;
    float sr0 = g[0], sr1 = g[1], sr2 = g[2];
    float q0 = g[3], q1 = g[4], q2 = g[5], q3 = g[6];
    float sh00=g[7],  sh01=g[8],  sh02=g[9],  sh03=g[10];
    float sh10=g[11], sh11=g[12], sh12=g[13], sh13=g[14];
    float sh20=g[15], sh21=g[16], sh22=g[17], sh23=g[18];

    // ---- scales ----
    float s0 = SCALE_MIN + (SCALE_MAX - SCALE_MIN) / (1.0f + __expf(-sr0));
    float s1 = SCALE_MIN + (SCALE_MAX - SCALE_MIN) / (1.0f + __expf(-sr1));
    float s2 = SCALE_MIN + (SCALE_MAX - SCALE_MIN) / (1.0f + __expf(-sr2));
    float dm = dep * mult;
    s0 *= dm; s1 *= dm; s2 *= dm;

    // ---- rotations (normalized quat, order w,x,y,z) ----
    float qn = sqrtf(q0*q0 + q1*q1 + q2*q2 + q3*q3) + EPS;
    float qi = 1.0f / qn;
    float qw = q0*qi, qx = q1*qi, qy = q2*qi, qz = q3*qi;

    // quat -> rotmat
    float r00 = 1.0f - 2.0f*(qy*qy + qz*qz);
    float r01 = 2.0f*(qx*qy - qw*qz);
    float r02 = 2.0f*(qx*qz + qw*qy);
    float r10 = 2.0f*(qx*qy + qw*qz);
    float r11 = 1.0f - 2.0f*(qx*qx + qz*qz);
    float r12 = 2.0f*(qy*qz - qw*qx);
    float r20 = 2.0f*(qx*qz - qw*qy);
    float r21 = 2.0f*(qy*qz + qw*qx);
    float r22 = 1.0f - 2.0f*(qx*qx + qy*qy);

    // ---- cov0 = R diag(s^2) R^T (symmetric) ----
    float v0 = s0*s0, v1 = s1*s1, v2 = s2*s2;
    float p00 = r00*r00*v0 + r01*r01*v1 + r02*r02*v2;
    float p01 = r00*r10*v0 + r01*r11*v1 + r02*r12*v2;
    float p02 = r00*r20*v0 + r01*r21*v1 + r02*r22*v2;
    float p11 = r10*r10*v0 + r11*r11*v1 + r12*r12*v2;
    float p12 = r10*r20*v0 + r11*r21*v1 + r12*r22*v2;
    float p22 = r20*r20*v0 + r21*r21*v1 + r22*r22*v2;

    // M = c2w * P
    float m00 = c00*p00 + c01*p01 + c02*p02;
    float m01 = c00*p01 + c01*p11 + c02*p12;
    float m02 = c00*p02 + c01*p12 + c02*p22;
    float m10 = c10*p00 + c11*p01 + c12*p02;
    float m11 = c10*p01 + c11*p11 + c12*p12;
    float m12 = c10*p02 + c11*p12 + c12*p22;
    float m20 = c20*p00 + c21*p01 + c22*p02;
    float m21 = c20*p01 + c21*p11 + c22*p12;
    float m22 = c20*p02 + c21*p12 + c22*p22;

    // cov = M * c2w^T (symmetric: mirror lower from upper)
    float q00 = m00*c00 + m01*c01 + m02*c02;
    float q01 = m00*c10 + m01*c11 + m02*c12;
    float q02 = m00*c20 + m01*c21 + m02*c22;
    float q11 = m10*c10 + m11*c11 + m12*c12;
    float q12 = m10*c20 + m11*c21 + m12*c22;
    float q22 = m20*c20 + m21*c21 + m22*c22;

    // ---- means ----
    float d0 = i00*uv.x + i01*uv.y + i02;
    float d1 = i10*uv.x + i11*uv.y + i12;
    float d2 = i20*uv.x + i21*uv.y + i22;
    float rn = rsqrtf(d0*d0 + d1*d1 + d2*d2);
    d0 *= rn; d1 *= rn; d2 *= rn;
    float w0 = c00*d0 + c01*d1 + c02*d2;
    float w1 = c10*d0 + c11*d1 + c12*d2;
    float w2 = c20*d0 + c21*d1 + c22*d2;
    float me0 = t0 + w0*dep;
    float me1 = t1 + w1*dep;
    float me2 = t2 + w2*dep;

    // ---- harmonics: sh0 + D1 @ (0.025*sh[:,1:4]) ----
    // D1[i][j] = c2w[p[i]][p[j]], p = [1,2,0]
    float D00=c11, D01=c12, D02=c10;
    float D10=c21, D11=c22, D12=c20;
    float D20=c01, D21=c02, D22=c00;
    const float msk = 0.1f * 0.25f;
    float a1 = msk*sh01, a2 = msk*sh02, a3 = msk*sh03;
    float b1 = msk*sh11, b2 = msk*sh12, b3 = msk*sh13;
    float e1 = msk*sh21, e2 = msk*sh22, e3 = msk*sh23;
    float4 h0 = make_float4(sh00, D00*a1 + D01*a2 + D02*a3,
                                  D10*a1 + D11*a2 + D12*a3,
                                  D20*a1 + D21*a2 + D22*a3);
    float4 h1 = make_float4(sh10, D00*b1 + D01*b2 + D02*b3,
                                  D10*b1 + D11*b2 + D12*b3,
                                  D20*b1 + D21*b2 + D22*b3);
    float4 h2 = make_float4(sh20, D00*e1 + D01*e2 + D02*e3,
                                  D10*e1 + D11*e2 + D12*e3,
                                  D20*e1 + D21*e2 + D22*e3);

    // ---- stores ----
    float* om = out + gid*3;
    om[0] = me0; om[1] = me1; om[2] = me2;

    float* oc = out + 3*BN + gid*9;
    oc[0]=q00; oc[1]=q01; oc[2]=q02;
    oc[3]=q01; oc[4]=q11; oc[5]=q12;
    oc[6]=q02; oc[7]=q12; oc[8]=q22;

    float4* oh = (float4*)(out + 12*BN + (long long)gid*12);
    oh[0] = h0; oh[1] = h1; oh[2] = h2;

    out[24*BN + gid] = op;

    float* os = out + 25*BN + gid*3;
    os[0] = s0; os[1] = s1; os[2] = s2;

    ((float4*)(out + 28*BN))[gid] = make_float4(qw, qx, qy, qz);
}

extern "C" void kernel_launch(void* const* d_in, const int* in_sizes, int n_in,
                              void* d_out, int out_size, void* d_ws, size_t ws_size,
                              hipStream_t stream) {
    const float* ext   = (const float*)d_in[0];
    const float* intr  = (const float*)d_in[1];
    const float* coord = (const float*)d_in[2];
    const float* depth = (const float*)d_in[3];
    const float* opac  = (const float*)d_in[4];
    const float* rawg  = (const float*)d_in[5];
    const int*   hp    = (const int*)d_in[6];
    const int*   wp    = (const int*)d_in[7];

    int BN = in_sizes[3];            // B*N
    int B  = in_sizes[0] / 16;       // extrinsics: B*1*4*4
    int N  = BN / B;
    int blocks = (BN + 255) / 256;
    int bpb = (N + 255) / 256;       // blocks per batch (N % 256 == 0 here)

    mono_gaussian_adapter_kernel<<<blocks, 256, 0, stream>>>(
        ext, intr, coord, depth, opac, rawg, hp, wp,
        (float*)d_out, bpb, BN);
}

// Round 2
// 226.712 us; speedup vs baseline: 1.0289x; 1.0289x over previous
//
#include <hip/hip_runtime.h>
#include <math.h>

#define SCALE_MIN 0.5f
#define SCALE_MAX 15.0f
#define MULTIPLIER 0.1f
#define EPS 1e-8f

// Output layout (flat concat, f32):
//   means      [BN*3]  @ 0
//   cov        [BN*9]  @ 3*BN
//   harmonics  [BN*12] @ 12*BN
//   opacities  [BN*1]  @ 24*BN
//   scales     [BN*3]  @ 25*BN
//   rotations  [BN*4]  @ 28*BN
//
// Strategy: one thread per gaussian, 256 threads/block, BN % 256 == 0.
// All odd-stride global traffic goes through LDS so every global memory
// instruction is lane-contiguous float4 (16 B/lane coalescing sweet spot).
// LDS strides are odd (19, 3, 9) or b128-at-48B => <=2-way bank aliasing (free).

#define G 256  // gaussians per block

// LDS section offsets (floats) for the output staging phase
#define L_MEAN  0            // 3*G  = 768
#define L_COV   768          // 9*G  = 2304
#define L_HARM  3072         // 12*G = 3072
#define L_SCALE 6144         // 3*G  = 768
#define L_TOT   6912         // 27648 B; input phase needs 19*G = 4864 floats

__global__ __launch_bounds__(256) void mono_gaussian_adapter_kernel(
    const float* __restrict__ ext,    // B*16 (B,1,4,4)
    const float* __restrict__ intr,   // B*9  (B,1,3,3)
    const float* __restrict__ coord,  // BN*2
    const float* __restrict__ depth,  // BN
    const float* __restrict__ opac,   // BN
    const float* __restrict__ rawg,   // BN*19
    const int* __restrict__ hp,
    const int* __restrict__ wp,
    float* __restrict__ out,
    int bpb,                          // blocks per batch (N/256)
    int BN)
{
    __shared__ float lds[L_TOT];

    const int tid = threadIdx.x;
    const int blk = blockIdx.x;
    const int gid = blk * G + tid;
    const int b = blk / bpb;          // block-uniform -> scalar path

    // ---- stage rawg block (256*19 floats, float4-aligned) into LDS ----
    {
        const float4* gin = (const float4*)(rawg + (long long)blk * (G * 19));
        float4* l4 = (float4*)lds;
        #pragma unroll
        for (int i = 0; i < 5; ++i) {
            int idx = tid + i * 256;
            if (idx < (G * 19 / 4)) l4[idx] = gin[idx];
        }
    }

    float inv_w = 1.0f / (float)wp[0];
    float inv_h = 1.0f / (float)hp[0];

    // ---- per-batch (block-uniform) constants ----
    const float* E = ext + b * 16;
    float c00=E[0],  c01=E[1],  c02=E[2],  t0=E[3];
    float c10=E[4],  c11=E[5],  c12=E[6],  t1=E[7];
    float c20=E[8],  c21=E[9],  c22=E[10], t2=E[11];

    const float* Kb = intr + b * 9;
    float k00=Kb[0],k01=Kb[1],k02=Kb[2];
    float k10=Kb[3],k11=Kb[4],k12=Kb[5];
    float k20=Kb[6],k21=Kb[7],k22=Kb[8];

    float det2 = k00*k11 - k01*k10;
    float mult = MULTIPLIER * ((k11*inv_w - k01*inv_h) + (k00*inv_h - k10*inv_w)) / det2;

    float det3 = k00*(k11*k22 - k12*k21)
               + k01*(k12*k20 - k10*k22)
               + k02*(k10*k21 - k11*k20);
    float id3 = 1.0f / det3;
    float i00 = (k11*k22 - k12*k21)*id3;
    float i01 = (k02*k21 - k01*k22)*id3;
    float i02 = (k01*k12 - k02*k11)*id3;
    float i10 = (k12*k20 - k10*k22)*id3;
    float i11 = (k00*k22 - k02*k20)*id3;
    float i12 = (k02*k10 - k00*k12)*id3;
    float i20 = (k10*k21 - k11*k20)*id3;
    float i21 = (k01*k20 - k00*k21)*id3;
    float i22 = (k00*k11 - k01*k10)*id3;

    // ---- per-gaussian coalesced loads (stride-1/2 sections: direct) ----
    float2 uv = ((const float2*)coord)[gid];
    float dep = depth[gid];
    float op  = opac[gid];

    __syncthreads();   // rawg staged

    // ---- per-thread fragment from LDS (stride 19 = odd -> conflict-free) ----
    const float* g = lds + tid * 19;
    float sr0 = g[0], sr1 = g[1], sr2 = g[2];
    float q0 = g[3], q1 = g[4], q2 = g[5], q3 = g[6];
    float sh00=g[7],  sh01=g[8],  sh02=g[9],  sh03=g[10];
    float sh10=g[11], sh11=g[12], sh12=g[13], sh13=g[14];
    float sh20=g[15], sh21=g[16], sh22=g[17], sh23=g[18];

    __syncthreads();   // everyone done reading before LDS is reused for output

    // ---- scales ----
    float s0 = SCALE_MIN + (SCALE_MAX - SCALE_MIN) / (1.0f + __expf(-sr0));
    float s1 = SCALE_MIN + (SCALE_MAX - SCALE_MIN) / (1.0f + __expf(-sr1));
    float s2 = SCALE_MIN + (SCALE_MAX - SCALE_MIN) / (1.0f + __expf(-sr2));
    float dm = dep * mult;
    s0 *= dm; s1 *= dm; s2 *= dm;

    // ---- rotations (normalized quat, order w,x,y,z) ----
    float qn = sqrtf(q0*q0 + q1*q1 + q2*q2 + q3*q3) + EPS;
    float qi = 1.0f / qn;
    float qw = q0*qi, qx = q1*qi, qy = q2*qi, qz = q3*qi;

    float r00 = 1.0f - 2.0f*(qy*qy + qz*qz);
    float r01 = 2.0f*(qx*qy - qw*qz);
    float r02 = 2.0f*(qx*qz + qw*qy);
    float r10 = 2.0f*(qx*qy + qw*qz);
    float r11 = 1.0f - 2.0f*(qx*qx + qz*qz);
    float r12 = 2.0f*(qy*qz - qw*qx);
    float r20 = 2.0f*(qx*qz - qw*qy);
    float r21 = 2.0f*(qy*qz + qw*qx);
    float r22 = 1.0f - 2.0f*(qx*qx + qy*qy);

    // ---- cov0 = R diag(s^2) R^T ----
    float v0 = s0*s0, v1 = s1*s1, v2 = s2*s2;
    float p00 = r00*r00*v0 + r01*r01*v1 + r02*r02*v2;
    float p01 = r00*r10*v0 + r01*r11*v1 + r02*r12*v2;
    float p02 = r00*r20*v0 + r01*r21*v1 + r02*r22*v2;
    float p11 = r10*r10*v0 + r11*r11*v1 + r12*r12*v2;
    float p12 = r10*r20*v0 + r11*r21*v1 + r12*r22*v2;
    float p22 = r20*r20*v0 + r21*r21*v1 + r22*r22*v2;

    float m00 = c00*p00 + c01*p01 + c02*p02;
    float m01 = c00*p01 + c01*p11 + c02*p12;
    float m02 = c00*p02 + c01*p12 + c02*p22;
    float m10 = c10*p00 + c11*p01 + c12*p02;
    float m11 = c10*p01 + c11*p11 + c12*p12;
    float m12 = c10*p02 + c11*p12 + c12*p22;
    float m20 = c20*p00 + c21*p01 + c22*p02;
    float m21 = c20*p01 + c21*p11 + c22*p12;
    float m22 = c20*p02 + c21*p12 + c22*p22;

    float q00 = m00*c00 + m01*c01 + m02*c02;
    float q01 = m00*c10 + m01*c11 + m02*c12;
    float q02 = m00*c20 + m01*c21 + m02*c22;
    float q11 = m10*c10 + m11*c11 + m12*c12;
    float q12 = m10*c20 + m11*c21 + m12*c22;
    float q22 = m20*c20 + m21*c21 + m22*c22;

    // ---- means ----
    float d0 = i00*uv.x + i01*uv.y + i02;
    float d1 = i10*uv.x + i11*uv.y + i12;
    float d2 = i20*uv.x + i21*uv.y + i22;
    float rn = rsqrtf(d0*d0 + d1*d1 + d2*d2);
    d0 *= rn; d1 *= rn; d2 *= rn;
    float w0 = c00*d0 + c01*d1 + c02*d2;
    float w1 = c10*d0 + c11*d1 + c12*d2;
    float w2 = c20*d0 + c21*d1 + c22*d2;
    float me0 = t0 + w0*dep;
    float me1 = t1 + w1*dep;
    float me2 = t2 + w2*dep;

    // ---- harmonics: [sh0 | D1 @ (0.025*sh1)] ; D1[i][j]=c2w[p[i]][p[j]], p=[1,2,0]
    float D00=c11, D01=c12, D02=c10;
    float D10=c21, D11=c22, D12=c20;
    float D20=c01, D21=c02, D22=c00;
    const float msk = 0.1f * 0.25f;
    float a1 = msk*sh01, a2 = msk*sh02, a3 = msk*sh03;
    float b1 = msk*sh11, b2 = msk*sh12, b3 = msk*sh13;
    float e1 = msk*sh21, e2 = msk*sh22, e3 = msk*sh23;
    float4 h0 = make_float4(sh00, D00*a1 + D01*a2 + D02*a3,
                                  D10*a1 + D11*a2 + D12*a3,
                                  D20*a1 + D21*a2 + D22*a3);
    float4 h1 = make_float4(sh10, D00*b1 + D01*b2 + D02*b3,
                                  D10*b1 + D11*b2 + D12*b3,
                                  D20*b1 + D21*b2 + D22*b3);
    float4 h2 = make_float4(sh20, D00*e1 + D01*e2 + D02*e3,
                                  D10*e1 + D11*e2 + D12*e3,
                                  D20*e1 + D21*e2 + D22*e3);

    // ---- direct stores for already-coalesced sections ----
    out[24*BN + gid] = op;                                     // stride-1
    ((float4*)(out + 28*BN))[gid] = make_float4(qw, qx, qy, qz); // contiguous 16B

    // ---- stage odd-stride sections in LDS ----
    {
        float* lm = lds + L_MEAN + tid * 3;      // stride 3 (odd) -> free
        lm[0] = me0; lm[1] = me1; lm[2] = me2;

        float* lc = lds + L_COV + tid * 9;       // stride 9 (odd) -> free
        lc[0]=q00; lc[1]=q01; lc[2]=q02;
        lc[3]=q01; lc[4]=q11; lc[5]=q12;
        lc[6]=q02; lc[7]=q12; lc[8]=q22;

        float4* lh = (float4*)(lds + L_HARM + tid * 12); // b128 @48B stride -> <=2-way
        lh[0] = h0; lh[1] = h1; lh[2] = h2;

        float* ls = lds + L_SCALE + tid * 3;     // stride 3 (odd) -> free
        ls[0] = s0; ls[1] = s1; ls[2] = s2;
    }
    __syncthreads();

    // ---- cooperative lane-contiguous float4 writeback ----
    {
        const float4* l4 = (const float4*)lds;
        // means: 192 float4  @ out + blk*768
        float4* gm = (float4*)(out + (long long)blk * (3 * G));
        if (tid < 192) gm[tid] = l4[(L_MEAN / 4) + tid];
        // scales: 192 float4 @ out + 25BN + blk*768
        float4* gs = (float4*)(out + 25LL * BN + (long long)blk * (3 * G));
        if (tid < 192) gs[tid] = l4[(L_SCALE / 4) + tid];
        // cov: 576 float4 @ out + 3BN + blk*2304
        float4* gc = (float4*)(out + 3LL * BN + (long long)blk * (9 * G));
        #pragma unroll
        for (int i = 0; i < 3; ++i) {
            int idx = tid + i * 256;
            if (idx < 576) gc[idx] = l4[(L_COV / 4) + idx];
        }
        // harmonics: 768 float4 @ out + 12BN + blk*3072
        float4* gh = (float4*)(out + 12LL * BN + (long long)blk * (12 * G));
        #pragma unroll
        for (int i = 0; i < 3; ++i) {
            int idx = tid + i * 256;
            gh[idx] = l4[(L_HARM / 4) + idx];
        }
    }
}

extern "C" void kernel_launch(void* const* d_in, const int* in_sizes, int n_in,
                              void* d_out, int out_size, void* d_ws, size_t ws_size,
                              hipStream_t stream) {
    const float* ext   = (const float*)d_in[0];
    const float* intr  = (const float*)d_in[1];
    const float* coord = (const float*)d_in[2];
    const float* depth = (const float*)d_in[3];
    const float* opac  = (const float*)d_in[4];
    const float* rawg  = (const float*)d_in[5];
    const int*   hp    = (const int*)d_in[6];
    const int*   wp    = (const int*)d_in[7];

    int BN = in_sizes[3];            // B*N (1048576 here, % 256 == 0)
    int B  = in_sizes[0] / 16;       // extrinsics: B*1*4*4
    int N  = BN / B;
    int blocks = BN / 256;           // full blocks only (BN % 256 == 0)
    int bpb = N / 256;               // blocks per batch

    mono_gaussian_adapter_kernel<<<blocks, 256, 0, stream>>>(
        ext, intr, coord, depth, opac, rawg, hp, wp,
        (float*)d_out, bpb, BN);
}

// Round 4
// 213.912 us; speedup vs baseline: 1.0905x; 1.0598x over previous
//
#include <hip/hip_runtime.h>
#include <math.h>

#define SCALE_MIN 0.5f
#define SCALE_MAX 15.0f
#define MULTIPLIER 0.1f
#define EPS 1e-8f

// native vector types (class-type float4 is rejected by nontemporal builtins)
typedef float v4f __attribute__((ext_vector_type(4)));
typedef float v2f __attribute__((ext_vector_type(2)));

// Output layout (flat concat, f32):
//   means      [BN*3]  @ 0
//   cov        [BN*9]  @ 3*BN
//   harmonics  [BN*12] @ 12*BN
//   opacities  [BN*1]  @ 24*BN
//   scales     [BN*3]  @ 25*BN
//   rotations  [BN*4]  @ 28*BN
//
// One thread per gaussian, 256/block. All odd-stride global traffic goes
// through LDS so every global memory instruction is lane-contiguous 16B.
// All global loads/stores are nontemporal (pure streaming, zero reuse).

#define G 256  // gaussians per block

// LDS section offsets (floats) for the output staging phase
#define L_MEAN  0            // 3*G  = 768
#define L_COV   768          // 9*G  = 2304
#define L_HARM  3072         // 12*G = 3072
#define L_SCALE 6144         // 3*G  = 768
#define L_TOT   6912         // 27648 B; input phase reuses first 19*G floats

__global__ __launch_bounds__(256) void mono_gaussian_adapter_kernel(
    const float* __restrict__ ext,    // B*16 (B,1,4,4)
    const float* __restrict__ intr,   // B*9  (B,1,3,3)
    const float* __restrict__ coord,  // BN*2
    const float* __restrict__ depth,  // BN
    const float* __restrict__ opac,   // BN
    const float* __restrict__ rawg,   // BN*19
    const int* __restrict__ hp,
    const int* __restrict__ wp,
    float* __restrict__ out,
    int bpb,                          // blocks per batch (N/256)
    int BN)
{
    __shared__ float lds[L_TOT];

    const int tid = threadIdx.x;
    const int blk = blockIdx.x;
    const int gid = blk * G + tid;
    const int b = blk / bpb;          // block-uniform -> scalar path

    // ---- stage rawg block (256*19 floats = 1216 v4f) into LDS, NT ----
    {
        const v4f* gin = (const v4f*)(rawg + (long long)blk * (G * 19));
        v4f* l4 = (v4f*)lds;
        #pragma unroll
        for (int i = 0; i < 4; ++i) {
            int idx = tid + i * 256;
            l4[idx] = __builtin_nontemporal_load(gin + idx);
        }
        {   // tail: 1216 - 1024 = 192 v4f
            int idx = tid + 4 * 256;
            if (idx < (G * 19 / 4))
                l4[idx] = __builtin_nontemporal_load(gin + idx);
        }
    }

    float inv_w = 1.0f / (float)wp[0];
    float inv_h = 1.0f / (float)hp[0];

    // ---- per-batch (block-uniform) constants ----
    const float* E = ext + b * 16;
    float c00=E[0],  c01=E[1],  c02=E[2],  t0=E[3];
    float c10=E[4],  c11=E[5],  c12=E[6],  t1=E[7];
    float c20=E[8],  c21=E[9],  c22=E[10], t2=E[11];

    const float* Kb = intr + b * 9;
    float k00=Kb[0],k01=Kb[1],k02=Kb[2];
    float k10=Kb[3],k11=Kb[4],k12=Kb[5];
    float k20=Kb[6],k21=Kb[7],k22=Kb[8];

    float det2 = k00*k11 - k01*k10;
    float mult = MULTIPLIER * ((k11*inv_w - k01*inv_h) + (k00*inv_h - k10*inv_w)) / det2;

    float det3 = k00*(k11*k22 - k12*k21)
               + k01*(k12*k20 - k10*k22)
               + k02*(k10*k21 - k11*k20);
    float id3 = 1.0f / det3;
    float i00 = (k11*k22 - k12*k21)*id3;
    float i01 = (k02*k21 - k01*k22)*id3;
    float i02 = (k01*k12 - k02*k11)*id3;
    float i10 = (k12*k20 - k10*k22)*id3;
    float i11 = (k00*k22 - k02*k20)*id3;
    float i12 = (k02*k10 - k00*k12)*id3;
    float i20 = (k10*k21 - k11*k20)*id3;
    float i21 = (k01*k20 - k00*k21)*id3;
    float i22 = (k00*k11 - k01*k10)*id3;

    // ---- per-gaussian coalesced loads (stride-1/2 sections: direct, NT) ----
    v2f uv = __builtin_nontemporal_load((const v2f*)coord + gid);
    float dep = __builtin_nontemporal_load(depth + gid);
    float op  = __builtin_nontemporal_load(opac + gid);

    __syncthreads();   // rawg staged

    // ---- per-thread fragment from LDS (stride 19 = odd -> conflict-free) ----
    const float* g = lds + tid * 19;
    float sr0 = g[0], sr1 = g[1], sr2 = g[2];
    float q0 = g[3], q1 = g[4], q2 = g[5], q3 = g[6];
    float sh00=g[7],  sh01=g[8],  sh02=g[9],  sh03=g[10];
    float sh10=g[11], sh11=g[12], sh12=g[13], sh13=g[14];
    float sh20=g[15], sh21=g[16], sh22=g[17], sh23=g[18];

    __syncthreads();   // everyone done reading before LDS reuse for output

    // ---- scales ----
    float s0 = SCALE_MIN + (SCALE_MAX - SCALE_MIN) / (1.0f + __expf(-sr0));
    float s1 = SCALE_MIN + (SCALE_MAX - SCALE_MIN) / (1.0f + __expf(-sr1));
    float s2 = SCALE_MIN + (SCALE_MAX - SCALE_MIN) / (1.0f + __expf(-sr2));
    float dm = dep * mult;
    s0 *= dm; s1 *= dm; s2 *= dm;

    // ---- rotations (normalized quat, order w,x,y,z) ----
    float qn = sqrtf(q0*q0 + q1*q1 + q2*q2 + q3*q3) + EPS;
    float qi = 1.0f / qn;
    float qw = q0*qi, qx = q1*qi, qy = q2*qi, qz = q3*qi;

    float r00 = 1.0f - 2.0f*(qy*qy + qz*qz);
    float r01 = 2.0f*(qx*qy - qw*qz);
    float r02 = 2.0f*(qx*qz + qw*qy);
    float r10 = 2.0f*(qx*qy + qw*qz);
    float r11 = 1.0f - 2.0f*(qx*qx + qz*qz);
    float r12 = 2.0f*(qy*qz - qw*qx);
    float r20 = 2.0f*(qx*qz - qw*qy);
    float r21 = 2.0f*(qy*qz + qw*qx);
    float r22 = 1.0f - 2.0f*(qx*qx + qy*qy);

    // ---- cov0 = R diag(s^2) R^T ----
    float v0 = s0*s0, v1 = s1*s1, v2 = s2*s2;
    float p00 = r00*r00*v0 + r01*r01*v1 + r02*r02*v2;
    float p01 = r00*r10*v0 + r01*r11*v1 + r02*r12*v2;
    float p02 = r00*r20*v0 + r01*r21*v1 + r02*r22*v2;
    float p11 = r10*r10*v0 + r11*r11*v1 + r12*r12*v2;
    float p12 = r10*r20*v0 + r11*r21*v1 + r12*r22*v2;
    float p22 = r20*r20*v0 + r21*r21*v1 + r22*r22*v2;

    float m00 = c00*p00 + c01*p01 + c02*p02;
    float m01 = c00*p01 + c01*p11 + c02*p12;
    float m02 = c00*p02 + c01*p12 + c02*p22;
    float m10 = c10*p00 + c11*p01 + c12*p02;
    float m11 = c10*p01 + c11*p11 + c12*p12;
    float m12 = c10*p02 + c11*p12 + c12*p22;
    float m20 = c20*p00 + c21*p01 + c22*p02;
    float m21 = c20*p01 + c21*p11 + c22*p12;
    float m22 = c20*p02 + c21*p12 + c22*p22;

    float q00 = m00*c00 + m01*c01 + m02*c02;
    float q01 = m00*c10 + m01*c11 + m02*c12;
    float q02 = m00*c20 + m01*c21 + m02*c22;
    float q11 = m10*c10 + m11*c11 + m12*c12;
    float q12 = m10*c20 + m11*c21 + m12*c22;
    float q22 = m20*c20 + m21*c21 + m22*c22;

    // ---- means ----
    float d0 = i00*uv.x + i01*uv.y + i02;
    float d1 = i10*uv.x + i11*uv.y + i12;
    float d2 = i20*uv.x + i21*uv.y + i22;
    float rn = rsqrtf(d0*d0 + d1*d1 + d2*d2);
    d0 *= rn; d1 *= rn; d2 *= rn;
    float w0 = c00*d0 + c01*d1 + c02*d2;
    float w1 = c10*d0 + c11*d1 + c12*d2;
    float w2 = c20*d0 + c21*d1 + c22*d2;
    float me0 = t0 + w0*dep;
    float me1 = t1 + w1*dep;
    float me2 = t2 + w2*dep;

    // ---- harmonics: [sh0 | D1 @ (0.025*sh1)]; D1[i][j]=c2w[p[i]][p[j]], p=[1,2,0]
    float D00=c11, D01=c12, D02=c10;
    float D10=c21, D11=c22, D12=c20;
    float D20=c01, D21=c02, D22=c00;
    const float msk = 0.1f * 0.25f;
    float a1 = msk*sh01, a2 = msk*sh02, a3 = msk*sh03;
    float b1 = msk*sh11, b2 = msk*sh12, b3 = msk*sh13;
    float e1 = msk*sh21, e2 = msk*sh22, e3 = msk*sh23;
    v4f h0 = { sh00, D00*a1 + D01*a2 + D02*a3,
                     D10*a1 + D11*a2 + D12*a3,
                     D20*a1 + D21*a2 + D22*a3 };
    v4f h1 = { sh10, D00*b1 + D01*b2 + D02*b3,
                     D10*b1 + D11*b2 + D12*b3,
                     D20*b1 + D21*b2 + D22*b3 };
    v4f h2 = { sh20, D00*e1 + D01*e2 + D02*e3,
                     D10*e1 + D11*e2 + D12*e3,
                     D20*e1 + D21*e2 + D22*e3 };

    // ---- direct NT stores for already-coalesced sections ----
    __builtin_nontemporal_store(op, out + 24*BN + gid);
    v4f rq = { qw, qx, qy, qz };
    __builtin_nontemporal_store(rq, (v4f*)(out + 28LL*BN) + gid);

    // ---- stage odd-stride sections in LDS ----
    {
        float* lm = lds + L_MEAN + tid * 3;      // stride 3 (odd) -> free
        lm[0] = me0; lm[1] = me1; lm[2] = me2;

        float* lc = lds + L_COV + tid * 9;       // stride 9 (odd) -> free
        lc[0]=q00; lc[1]=q01; lc[2]=q02;
        lc[3]=q01; lc[4]=q11; lc[5]=q12;
        lc[6]=q02; lc[7]=q12; lc[8]=q22;

        v4f* lh = (v4f*)(lds + L_HARM + tid * 12); // b128 @48B -> <=2-way
        lh[0] = h0; lh[1] = h1; lh[2] = h2;

        float* ls = lds + L_SCALE + tid * 3;     // stride 3 (odd) -> free
        ls[0] = s0; ls[1] = s1; ls[2] = s2;
    }
    __syncthreads();

    // ---- cooperative lane-contiguous 16B NT writeback ----
    {
        const v4f* l4 = (const v4f*)lds;
        // means+scales: 192 v4f each
        v4f* gm = (v4f*)(out + (long long)blk * (3 * G));
        v4f* gs = (v4f*)(out + 25LL * BN + (long long)blk * (3 * G));
        if (tid < 192) {
            __builtin_nontemporal_store(l4[(L_MEAN / 4) + tid], gm + tid);
            __builtin_nontemporal_store(l4[(L_SCALE / 4) + tid], gs + tid);
        }
        // cov: 576 v4f @ out + 3BN + blk*2304
        v4f* gc = (v4f*)(out + 3LL * BN + (long long)blk * (9 * G));
        #pragma unroll
        for (int i = 0; i < 2; ++i) {
            int idx = tid + i * 256;
            __builtin_nontemporal_store(l4[(L_COV / 4) + idx], gc + idx);
        }
        {   int idx = tid + 512;
            if (idx < 576)
                __builtin_nontemporal_store(l4[(L_COV / 4) + idx], gc + idx);
        }
        // harmonics: 768 v4f @ out + 12BN + blk*3072
        v4f* gh = (v4f*)(out + 12LL * BN + (long long)blk * (12 * G));
        #pragma unroll
        for (int i = 0; i < 3; ++i) {
            int idx = tid + i * 256;
            __builtin_nontemporal_store(l4[(L_HARM / 4) + idx], gh + idx);
        }
    }
}

extern "C" void kernel_launch(void* const* d_in, const int* in_sizes, int n_in,
                              void* d_out, int out_size, void* d_ws, size_t ws_size,
                              hipStream_t stream) {
    const float* ext   = (const float*)d_in[0];
    const float* intr  = (const float*)d_in[1];
    const float* coord = (const float*)d_in[2];
    const float* depth = (const float*)d_in[3];
    const float* opac  = (const float*)d_in[4];
    const float* rawg  = (const float*)d_in[5];
    const int*   hp    = (const int*)d_in[6];
    const int*   wp    = (const int*)d_in[7];

    int BN = in_sizes[3];            // B*N (1048576 here, % 256 == 0)
    int B  = in_sizes[0] / 16;       // extrinsics: B*1*4*4
    int N  = BN / B;
    int blocks = BN / 256;           // BN % 256 == 0
    int bpb = N / 256;               // blocks per batch

    mono_gaussian_adapter_kernel<<<blocks, 256, 0, stream>>>(
        ext, intr, coord, depth, opac, rawg, hp, wp,
        (float*)d_out, bpb, BN);
}